// Round 1
// baseline (170.068 us; speedup 1.0000x reference)
//
#include <hip/hip_runtime.h>
#include <math.h>

#define Bsz 8
#define Udim 13
#define Vdim 13
#define Hdim 128
#define Wdim 160
#define HW (Hdim * Wdim)          // 20480
#define UV (Udim * Vdim)          // 169
#define TRUNC 4
#define NPIX (Bsz * HW)           // 163840

__global__ __launch_bounds__(256) void flow_regression_kernel(
    const float* __restrict__ x, float* __restrict__ out) {
    int p = blockIdx.x * 256 + threadIdx.x;
    if (p >= NPIX) return;
    int b  = p / HW;
    int hw = p - b * HW;

    const float* base = x + (size_t)b * UV * HW + hw;

    // ---- Pass 1: argmax over 169 planes (coalesced: lane i reads hw+i) ----
    float m = -INFINITY;
    int mi = 0;
    {
        const float* q = base;
        #pragma unroll 13
        for (int i = 0; i < UV; ++i) {
            float v = *q;
            q += HW;
            if (v > m) { m = v; mi = i; }   // strict > => first index on ties (argmax semantics)
        }
    }
    int ui = mi / Vdim;
    int vi = mi - ui * Vdim;

    // ---- Pass 2: masked softmax-weighted displacement, full re-scan ----
    // Full 169-scan with predication keeps control flow wave-uniform and loads
    // coalesced (per-pixel windows are random => window loops would diverge and
    // scatter). Re-read hits L2/L3.
    float sum = 0.f, wu = 0.f, wv = 0.f;
    {
        const float* q = base;
        for (int u = 0; u < Udim; ++u) {
            bool uin = (u - ui <= TRUNC) && (ui - u <= TRUNC);
            float du = (float)(u - 6);
            #pragma unroll
            for (int v = 0; v < Vdim; ++v) {
                float val = *q;
                q += HW;
                bool in = uin && (v - vi <= TRUNC) && (vi - v <= TRUNC);
                float e = in ? __expf(val - m) : 0.f;
                sum += e;
                wu  += e * du;
                wv  += e * (float)(v - 6);
            }
        }
    }
    float inv = 1.0f / sum;
    float* ob = out + (size_t)b * 2 * HW + hw;
    ob[0]  = wu * inv;   // flowU plane
    ob[HW] = wv * inv;   // flowV plane
}

extern "C" void kernel_launch(void* const* d_in, const int* in_sizes, int n_in,
                              void* d_out, int out_size, void* d_ws, size_t ws_size,
                              hipStream_t stream) {
    const float* x = (const float*)d_in[0];
    float* out = (float*)d_out;
    int nblocks = (NPIX + 255) / 256;   // 640
    flow_regression_kernel<<<nblocks, 256, 0, stream>>>(x, out);
}

// Round 2
// 158.339 us; speedup vs baseline: 1.0741x; 1.0741x over previous
//
#include <hip/hip_runtime.h>
#include <math.h>

#define Bsz 8
#define Udim 13
#define Vdim 13
#define Hdim 128
#define Wdim 160
#define HW (Hdim * Wdim)          // 20480
#define UV (Udim * Vdim)          // 169
#define TRUNC 4
#define NPIX (Bsz * HW)           // 163840 = 640 * 256 exactly

// Single-pass: hold all 169 (u,v) values per pixel in VGPRs (~169 regs),
// so the input is read from HBM exactly once. __launch_bounds__(256,2)
// => <=256 VGPRs/wave, 2 waves/SIMD, 8 waves/CU — plenty for a pure
// streaming load phase with 169 independent loads in flight per thread.
__global__ __launch_bounds__(256, 2) void flow_regression_kernel(
    const float* __restrict__ x, float* __restrict__ out) {
    int p = blockIdx.x * 256 + threadIdx.x;
    int b  = p / HW;
    int hw = p - b * HW;

    const float* base = x + (size_t)b * UV * HW + hw;

    // ---- Load all 169 planes into registers (coalesced, independent) ----
    float vals[UV];
    #pragma unroll
    for (int i = 0; i < UV; ++i) {
        vals[i] = base[(size_t)i * HW];
    }

    // ---- Argmax (strict > => first index on ties, matches jnp.argmax) ----
    float m = vals[0];
    int mi = 0;
    #pragma unroll
    for (int i = 1; i < UV; ++i) {
        if (vals[i] > m) { m = vals[i]; mi = i; }
    }
    int ui = mi / Vdim;
    int vi = mi - ui * Vdim;

    // ---- Masked softmax-weighted displacement, all from registers ----
    float sum = 0.f, wu = 0.f, wv = 0.f;
    #pragma unroll
    for (int u = 0; u < Udim; ++u) {
        // uin as 0/1 multiply lets rows factor; v-mask predicated per elem
        bool uin = (u - ui <= TRUNC) && (ui - u <= TRUNC);
        float rsum = 0.f, rwv = 0.f;
        #pragma unroll
        for (int v = 0; v < Vdim; ++v) {
            float val = vals[u * Vdim + v];
            bool vin = (v - vi <= TRUNC) && (vi - v <= TRUNC);
            float e = vin ? __expf(val - m) : 0.f;
            rsum += e;
            rwv  += e * (float)(v - 6);
        }
        if (uin) {
            sum += rsum;
            wu  += rsum * (float)(u - 6);
            wv  += rwv;
        }
    }
    float inv = 1.0f / sum;
    float* ob = out + (size_t)b * 2 * HW + hw;
    ob[0]  = wu * inv;   // flowU plane
    ob[HW] = wv * inv;   // flowV plane
}

extern "C" void kernel_launch(void* const* d_in, const int* in_sizes, int n_in,
                              void* d_out, int out_size, void* d_ws, size_t ws_size,
                              hipStream_t stream) {
    const float* x = (const float*)d_in[0];
    float* out = (float*)d_out;
    flow_regression_kernel<<<NPIX / 256, 256, 0, stream>>>(x, out);
}